// Round 1
// baseline (13389.447 us; speedup 1.0000x reference)
//
#include <hip/hip_runtime.h>

#define N_NODESC 100000
#define N_EDGESC 1600000
#define IN_CHC 64
#define HEADSC 8
#define OUT_CHC 16
#define HCC 128                      // HEADS*OUT_CH
#define E_TOTC (N_EDGESC + N_NODESC) // edges + self loops

__device__ __forceinline__ unsigned enc_f(float f) {
    unsigned u = __float_as_uint(f);
    return (u & 0x80000000u) ? ~u : (u | 0x80000000u);
}
__device__ __forceinline__ float dec_f(unsigned u) {
    u = (u & 0x80000000u) ? (u & 0x7FFFFFFFu) : ~u;
    return __uint_as_float(u);
}
__device__ __forceinline__ float lrelu(float v) {
    return v < 0.f ? 0.2f * v : v;
}

// ---- transpose W [128][64] -> WT [64][128] (k-major) ----
__global__ void wt_kernel(const float* __restrict__ W, float* __restrict__ WT) {
    int t = blockIdx.x * 256 + threadIdx.x;
    if (t < HCC * IN_CHC) {
        int k = t >> 7, c = t & 127;
        WT[t] = W[c * IN_CHC + k];
    }
}

// ---- projection GEMM: h[N][128] = x[N][64] @ W^T ----
// block: 256 threads, 128 rows/block. Thread tile 8 rows x 8 cols.
// rows: rg + 16*i (2-way LDS bank alias = free); cols: 4*cg+{0..3} and 64+4*cg+{0..3}.
__launch_bounds__(256, 2)
__global__ void proj_kernel(const float* __restrict__ x, const float* __restrict__ WT,
                            float* __restrict__ h) {
    __shared__ float xs[128][68];   // pad 4 -> 16B-aligned float4 rows, 2-way reads
    __shared__ float ws[64][128];   // k-major copy of WT (linear)
    const int t = threadIdx.x;
    const int row0 = blockIdx.x * 128;

    // stage WT -> LDS (coalesced, conflict-free linear float4)
    const float4* wt4 = (const float4*)WT;
    float4* ws4 = (float4*)&ws[0][0];
#pragma unroll
    for (int j = 0; j < 8; ++j) ws4[t + 256 * j] = wt4[t + 256 * j];

    // stage x tile (contiguous 32KB region), row-major padded
#pragma unroll
    for (int j = 0; j < 8; ++j) {
        int f = (t + 256 * j) * 4;      // flat float idx within tile
        int r = f >> 6, k = f & 63;
        int gr = row0 + r;
        if (gr >= N_NODESC) gr = N_NODESC - 1;   // clamp; stores guarded later
        float4 v = *(const float4*)&x[(size_t)gr * IN_CHC + k];
        *(float4*)&xs[r][k] = v;
    }
    __syncthreads();

    const int rg = t & 15;
    const int cg = t >> 4;
    float acc[8][8];
#pragma unroll
    for (int i = 0; i < 8; ++i)
#pragma unroll
        for (int j = 0; j < 8; ++j) acc[i][j] = 0.f;

#pragma unroll 4
    for (int k = 0; k < 64; ++k) {
        float xv[8];
#pragma unroll
        for (int i = 0; i < 8; ++i) xv[i] = xs[rg + 16 * i][k];
        float4 w0 = *(const float4*)&ws[k][4 * cg];
        float4 w1 = *(const float4*)&ws[k][64 + 4 * cg];
#pragma unroll
        for (int i = 0; i < 8; ++i) {
            acc[i][0] += xv[i] * w0.x; acc[i][1] += xv[i] * w0.y;
            acc[i][2] += xv[i] * w0.z; acc[i][3] += xv[i] * w0.w;
            acc[i][4] += xv[i] * w1.x; acc[i][5] += xv[i] * w1.y;
            acc[i][6] += xv[i] * w1.z; acc[i][7] += xv[i] * w1.w;
        }
    }

#pragma unroll
    for (int i = 0; i < 8; ++i) {
        int gr = row0 + rg + 16 * i;
        if (gr < N_NODESC) {
            float4 o0 = make_float4(acc[i][0], acc[i][1], acc[i][2], acc[i][3]);
            float4 o1 = make_float4(acc[i][4], acc[i][5], acc[i][6], acc[i][7]);
            *(float4*)&h[(size_t)gr * HCC + 4 * cg] = o0;
            *(float4*)&h[(size_t)gr * HCC + 64 + 4 * cg] = o1;
        }
    }
}

// ---- per-(node,head) attention halves: a_src/a_dst [N][8] ----
__global__ void a_kernel(const float* __restrict__ h,
                         const float* __restrict__ att_src, const float* __restrict__ att_dst,
                         float* __restrict__ a_src, float* __restrict__ a_dst) {
    int t = blockIdx.x * 256 + threadIdx.x;
    if (t >= N_NODESC * HEADSC) return;
    int hd = t & 7;
    const float4* hv = (const float4*)(h + (size_t)t * 16);   // n*128 + hd*16 == t*16
    const float4* s4 = (const float4*)(att_src + hd * 16);
    const float4* d4 = (const float4*)(att_dst + hd * 16);
    float as = 0.f, ad = 0.f;
#pragma unroll
    for (int j = 0; j < 4; ++j) {
        float4 v = hv[j], sv = s4[j], dv = d4[j];
        as += v.x * sv.x + v.y * sv.y + v.z * sv.z + v.w * sv.w;
        ad += v.x * dv.x + v.y * dv.y + v.z * dv.z + v.w * dv.w;
    }
    a_src[t] = as;
    a_dst[t] = ad;
}

// ---- pass A: segment max over dst (encoded uint atomicMax) ----
__global__ void edge_max_kernel(const int* __restrict__ ei,
                                const float* __restrict__ a_src, const float* __restrict__ a_dst,
                                unsigned* __restrict__ emax) {
    int e = blockIdx.x * 256 + threadIdx.x;
    if (e >= E_TOTC) return;
    int s, d;
    if (e < N_EDGESC) { s = ei[e]; d = ei[N_EDGESC + e]; }
    else              { s = d = e - N_EDGESC; }
    const float4* as4 = (const float4*)(a_src + (size_t)s * 8);
    const float4* ad4 = (const float4*)(a_dst + (size_t)d * 8);
    float4 s0 = as4[0], s1 = as4[1], d0 = ad4[0], d1 = ad4[1];
    float l[8] = { s0.x + d0.x, s0.y + d0.y, s0.z + d0.z, s0.w + d0.w,
                   s1.x + d1.x, s1.y + d1.y, s1.z + d1.z, s1.w + d1.w };
    unsigned* em = emax + (size_t)d * 8;
#pragma unroll
    for (int j = 0; j < 8; ++j) atomicMax(&em[j], enc_f(lrelu(l[j])));
}

// ---- pass B: segment sum of exp(l - max) ----
__global__ void edge_sum_kernel(const int* __restrict__ ei,
                                const float* __restrict__ a_src, const float* __restrict__ a_dst,
                                const unsigned* __restrict__ emax, float* __restrict__ denom) {
    int e = blockIdx.x * 256 + threadIdx.x;
    if (e >= E_TOTC) return;
    int s, d;
    if (e < N_EDGESC) { s = ei[e]; d = ei[N_EDGESC + e]; }
    else              { s = d = e - N_EDGESC; }
    const float4* as4 = (const float4*)(a_src + (size_t)s * 8);
    const float4* ad4 = (const float4*)(a_dst + (size_t)d * 8);
    float4 s0 = as4[0], s1 = as4[1], d0 = ad4[0], d1 = ad4[1];
    float l[8] = { s0.x + d0.x, s0.y + d0.y, s0.z + d0.z, s0.w + d0.w,
                   s1.x + d1.x, s1.y + d1.y, s1.z + d1.z, s1.w + d1.w };
    const unsigned* em = emax + (size_t)d * 8;
    float* dn = denom + (size_t)d * 8;
#pragma unroll
    for (int j = 0; j < 8; ++j) {
        float ev = expf(lrelu(l[j]) - dec_f(em[j]));
        atomicAdd(&dn[j], ev);
    }
}

// ---- pass C: weighted scatter-add aggregation. 8 lanes per edge (one per head). ----
__global__ void agg_kernel(const int* __restrict__ ei,
                           const float* __restrict__ a_src, const float* __restrict__ a_dst,
                           const unsigned* __restrict__ emax, const float* __restrict__ denom,
                           const float* __restrict__ h, float* __restrict__ out) {
    int t = blockIdx.x * 256 + threadIdx.x;
    int e = t >> 3, hd = t & 7;
    if (e >= E_TOTC) return;
    int s, d;
    if (e < N_EDGESC) { s = ei[e]; d = ei[N_EDGESC + e]; }
    else              { s = d = e - N_EDGESC; }
    float l = lrelu(a_src[(size_t)s * 8 + hd] + a_dst[(size_t)d * 8 + hd]);
    float m = dec_f(emax[(size_t)d * 8 + hd]);
    float alpha = expf(l - m) / (denom[(size_t)d * 8 + hd] + 1e-16f);
    const float4* h4 = (const float4*)(h + (size_t)s * HCC + hd * 16);
    float* ob = out + (size_t)d * HCC + hd * 16;
#pragma unroll
    for (int j = 0; j < 4; ++j) {
        float4 v = h4[j];
        atomicAdd(ob + 4 * j + 0, v.x * alpha);
        atomicAdd(ob + 4 * j + 1, v.y * alpha);
        atomicAdd(ob + 4 * j + 2, v.z * alpha);
        atomicAdd(ob + 4 * j + 3, v.w * alpha);
    }
}

// ---- epilogue: out = relu(out + bias) ----
__global__ void epi_kernel(float* __restrict__ out, const float* __restrict__ bias) {
    int i = blockIdx.x * 256 + threadIdx.x;   // float4 index
    if (i >= N_NODESC * 32) return;
    float4 v = ((float4*)out)[i];
    float4 b = ((const float4*)bias)[i & 31];
    v.x = fmaxf(v.x + b.x, 0.f); v.y = fmaxf(v.y + b.y, 0.f);
    v.z = fmaxf(v.z + b.z, 0.f); v.w = fmaxf(v.w + b.w, 0.f);
    ((float4*)out)[i] = v;
}

extern "C" void kernel_launch(void* const* d_in, const int* in_sizes, int n_in,
                              void* d_out, int out_size, void* d_ws, size_t ws_size,
                              hipStream_t stream) {
    const float* x       = (const float*)d_in[0];
    const int*   ei      = (const int*)d_in[1];
    const float* W       = (const float*)d_in[2];
    const float* att_src = (const float*)d_in[3];
    const float* att_dst = (const float*)d_in[4];
    const float* bias    = (const float*)d_in[5];
    float* out = (float*)d_out;

    float* ws      = (float*)d_ws;
    float* h       = ws;                         // 12,800,000 floats
    float* a_src   = ws + 12800000;              // 800,000
    float* a_dst   = a_src + 800000;             // 800,000
    unsigned* emax = (unsigned*)(a_dst + 800000);// 800,000
    float* denom   = (float*)(emax + 800000);    // 800,000
    float* WT      = denom + 800000;             // 8,192

    hipMemsetAsync(d_out, 0, (size_t)N_NODESC * HCC * sizeof(float), stream);
    hipMemsetAsync(emax, 0, 800000 * sizeof(unsigned), stream);   // 0 encodes < any float
    hipMemsetAsync(denom, 0, 800000 * sizeof(float), stream);

    wt_kernel<<<32, 256, 0, stream>>>(W, WT);
    proj_kernel<<<(N_NODESC + 127) / 128, 256, 0, stream>>>(x, WT, h);
    a_kernel<<<(N_NODESC * HEADSC + 255) / 256, 256, 0, stream>>>(h, att_src, att_dst, a_src, a_dst);
    edge_max_kernel<<<(E_TOTC + 255) / 256, 256, 0, stream>>>(ei, a_src, a_dst, emax);
    edge_sum_kernel<<<(E_TOTC + 255) / 256, 256, 0, stream>>>(ei, a_src, a_dst, emax, denom);
    agg_kernel<<<((size_t)E_TOTC * 8 + 255) / 256, 256, 0, stream>>>(ei, a_src, a_dst, emax, denom, h, out);
    epi_kernel<<<(N_NODESC * 32 + 255) / 256, 256, 0, stream>>>(out, bias);
}

// Round 2
// 713.550 us; speedup vs baseline: 18.7645x; 18.7645x over previous
//
#include <hip/hip_runtime.h>

#define N_NODESC 100000
#define N_EDGESC 1600000
#define IN_CHC 64
#define HEADSC 8
#define OUT_CHC 16
#define HCC 128                      // HEADS*OUT_CH
#define E_TOTC (N_EDGESC + N_NODESC) // edges + self loops
#define SCAN_NB 391                  // ceil(N_NODES/256)

__device__ __forceinline__ float lrelu(float v) {
    return v < 0.f ? 0.2f * v : v;
}

// ---- transpose W [128][64] -> WT [64][128] (k-major) ----
__global__ void wt_kernel(const float* __restrict__ W, float* __restrict__ WT) {
    int t = blockIdx.x * 256 + threadIdx.x;
    if (t < HCC * IN_CHC) {
        int k = t >> 7, c = t & 127;
        WT[t] = W[c * IN_CHC + k];
    }
}

// ---- projection GEMM: h[N][128] = x[N][64] @ W^T ----
__launch_bounds__(256, 2)
__global__ void proj_kernel(const float* __restrict__ x, const float* __restrict__ WT,
                            float* __restrict__ h) {
    __shared__ float xs[128][68];
    __shared__ float ws[64][128];
    const int t = threadIdx.x;
    const int row0 = blockIdx.x * 128;

    const float4* wt4 = (const float4*)WT;
    float4* ws4 = (float4*)&ws[0][0];
#pragma unroll
    for (int j = 0; j < 8; ++j) ws4[t + 256 * j] = wt4[t + 256 * j];

#pragma unroll
    for (int j = 0; j < 8; ++j) {
        int f = (t + 256 * j) * 4;
        int r = f >> 6, k = f & 63;
        int gr = row0 + r;
        if (gr >= N_NODESC) gr = N_NODESC - 1;
        float4 v = *(const float4*)&x[(size_t)gr * IN_CHC + k];
        *(float4*)&xs[r][k] = v;
    }
    __syncthreads();

    const int rg = t & 15;
    const int cg = t >> 4;
    float acc[8][8];
#pragma unroll
    for (int i = 0; i < 8; ++i)
#pragma unroll
        for (int j = 0; j < 8; ++j) acc[i][j] = 0.f;

#pragma unroll 4
    for (int k = 0; k < 64; ++k) {
        float xv[8];
#pragma unroll
        for (int i = 0; i < 8; ++i) xv[i] = xs[rg + 16 * i][k];
        float4 w0 = *(const float4*)&ws[k][4 * cg];
        float4 w1 = *(const float4*)&ws[k][64 + 4 * cg];
#pragma unroll
        for (int i = 0; i < 8; ++i) {
            acc[i][0] += xv[i] * w0.x; acc[i][1] += xv[i] * w0.y;
            acc[i][2] += xv[i] * w0.z; acc[i][3] += xv[i] * w0.w;
            acc[i][4] += xv[i] * w1.x; acc[i][5] += xv[i] * w1.y;
            acc[i][6] += xv[i] * w1.z; acc[i][7] += xv[i] * w1.w;
        }
    }

#pragma unroll
    for (int i = 0; i < 8; ++i) {
        int gr = row0 + rg + 16 * i;
        if (gr < N_NODESC) {
            float4 o0 = make_float4(acc[i][0], acc[i][1], acc[i][2], acc[i][3]);
            float4 o1 = make_float4(acc[i][4], acc[i][5], acc[i][6], acc[i][7]);
            *(float4*)&h[(size_t)gr * HCC + 4 * cg] = o0;
            *(float4*)&h[(size_t)gr * HCC + 64 + 4 * cg] = o1;
        }
    }
}

// ---- per-(node,head) attention halves: a_src/a_dst [N][8] ----
__global__ void a_kernel(const float* __restrict__ h,
                         const float* __restrict__ att_src, const float* __restrict__ att_dst,
                         float* __restrict__ a_src, float* __restrict__ a_dst) {
    int t = blockIdx.x * 256 + threadIdx.x;
    if (t >= N_NODESC * HEADSC) return;
    int hd = t & 7;
    const float4* hv = (const float4*)(h + (size_t)t * 16);
    const float4* s4 = (const float4*)(att_src + hd * 16);
    const float4* d4 = (const float4*)(att_dst + hd * 16);
    float as = 0.f, ad = 0.f;
#pragma unroll
    for (int j = 0; j < 4; ++j) {
        float4 v = hv[j], sv = s4[j], dv = d4[j];
        as += v.x * sv.x + v.y * sv.y + v.z * sv.z + v.w * sv.w;
        ad += v.x * dv.x + v.y * dv.y + v.z * dv.z + v.w * dv.w;
    }
    a_src[t] = as;
    a_dst[t] = ad;
}

// ---- CSR build: degree histogram over dst (incl. self loops) ----
__global__ void deg_kernel(const int* __restrict__ ei, int* __restrict__ deg) {
    int e = blockIdx.x * 256 + threadIdx.x;
    if (e >= E_TOTC) return;
    int d = (e < N_EDGESC) ? ei[N_EDGESC + e] : (e - N_EDGESC);
    atomicAdd(&deg[d], 1);
}

// ---- scan phase 1: per-block sums ----
__global__ void scan1_kernel(const int* __restrict__ deg, int* __restrict__ bsum) {
    __shared__ int lds[256];
    int i = blockIdx.x * 256 + threadIdx.x;
    lds[threadIdx.x] = (i < N_NODESC) ? deg[i] : 0;
    __syncthreads();
    for (int off = 128; off > 0; off >>= 1) {
        if (threadIdx.x < off) lds[threadIdx.x] += lds[threadIdx.x + off];
        __syncthreads();
    }
    if (threadIdx.x == 0) bsum[blockIdx.x] = lds[0];
}

// ---- scan phase 2: exclusive scan of block sums (single block) ----
__global__ void scan2_kernel(int* __restrict__ bsum) {
    __shared__ int lds[512];
    int t = threadIdx.x;
    lds[t] = (t < SCAN_NB) ? bsum[t] : 0;
    __syncthreads();
    for (int off = 1; off < 512; off <<= 1) {
        int u = 0;
        if (t >= off) u = lds[t - off];
        __syncthreads();
        if (t >= off) lds[t] += u;
        __syncthreads();
    }
    if (t < SCAN_NB) bsum[t] = (t == 0) ? 0 : lds[t - 1];
}

// ---- scan phase 3: per-element exclusive scan -> rowptr & cursor ----
__global__ void scan3_kernel(const int* __restrict__ deg, const int* __restrict__ bsum,
                             int* __restrict__ rowptr, int* __restrict__ cursor) {
    __shared__ int lds[256];
    int t = threadIdx.x;
    int i = blockIdx.x * 256 + t;
    int v = (i < N_NODESC) ? deg[i] : 0;
    lds[t] = v;
    __syncthreads();
    for (int off = 1; off < 256; off <<= 1) {
        int u = 0;
        if (t >= off) u = lds[t - off];
        __syncthreads();
        if (t >= off) lds[t] += u;
        __syncthreads();
    }
    int excl = bsum[blockIdx.x] + lds[t] - v;
    if (i < N_NODESC) { rowptr[i] = excl; cursor[i] = excl; }
    if (i == 0) rowptr[N_NODESC] = E_TOTC;
}

// ---- scatter edges into CSR order (src ids per dst segment) ----
__global__ void scatter_kernel(const int* __restrict__ ei, int* __restrict__ cursor,
                               int* __restrict__ colsrc) {
    int e = blockIdx.x * 256 + threadIdx.x;
    if (e >= E_TOTC) return;
    int s, d;
    if (e < N_EDGESC) { s = ei[e]; d = ei[N_EDGESC + e]; }
    else              { s = d = e - N_EDGESC; }
    int pos = atomicAdd(&cursor[d], 1);
    colsrc[pos] = s;
}

// ---- gather aggregation: 128 threads own one dst node's 128 channels ----
// loop1: per-head max; loop2: denom + unnormalized sum; epilogue: bias+relu.
__launch_bounds__(256, 8)
__global__ void agg_csr_kernel(const int* __restrict__ rowptr, const int* __restrict__ colsrc,
                               const float* __restrict__ a_src, const float* __restrict__ a_dst,
                               const float* __restrict__ h, const float* __restrict__ bias,
                               float* __restrict__ out) {
    int t = threadIdx.x;
    int n = blockIdx.x * 2 + (t >> 7);
    int c = t & 127, hd = c >> 4;
    int beg = rowptr[n], end = rowptr[n + 1];
    float ad = a_dst[(size_t)n * 8 + hd];

    float m = -1e30f;
    for (int p = beg; p < end; ++p) {
        int s = colsrc[p];
        m = fmaxf(m, lrelu(a_src[(size_t)s * 8 + hd] + ad));
    }
    float den = 0.f, acc = 0.f;
    for (int p = beg; p < end; ++p) {
        int s = colsrc[p];
        float e = __expf(lrelu(a_src[(size_t)s * 8 + hd] + ad) - m);
        den += e;
        acc += e * h[(size_t)s * HCC + c];
    }
    out[(size_t)n * HCC + c] = fmaxf(acc / (den + 1e-16f) + bias[c], 0.f);
}

extern "C" void kernel_launch(void* const* d_in, const int* in_sizes, int n_in,
                              void* d_out, int out_size, void* d_ws, size_t ws_size,
                              hipStream_t stream) {
    const float* x       = (const float*)d_in[0];
    const int*   ei      = (const int*)d_in[1];
    const float* W       = (const float*)d_in[2];
    const float* att_src = (const float*)d_in[3];
    const float* att_dst = (const float*)d_in[4];
    const float* bias    = (const float*)d_in[5];
    float* out = (float*)d_out;

    float* ws    = (float*)d_ws;
    float* h     = ws;                    // 12,800,000 floats
    float* a_src = ws + 12800000;         //    800,000
    float* a_dst = a_src + 800000;        //    800,000
    float* WT    = a_dst + 800000;        //      8,192
    int* ibase   = (int*)(WT + 8192);
    int* deg     = ibase;                 //    100,000
    int* rowptr  = deg + 100000;          //    100,001
    int* cursor  = rowptr + 100001;       //    100,000
    int* bsum    = cursor + 100000;       //        512
    int* colsrc  = bsum + 512;            //  1,700,000

    hipMemsetAsync(deg, 0, 100000 * sizeof(int), stream);

    wt_kernel<<<32, 256, 0, stream>>>(W, WT);
    proj_kernel<<<(N_NODESC + 127) / 128, 256, 0, stream>>>(x, WT, h);
    a_kernel<<<(N_NODESC * HEADSC + 255) / 256, 256, 0, stream>>>(h, att_src, att_dst, a_src, a_dst);

    deg_kernel<<<(E_TOTC + 255) / 256, 256, 0, stream>>>(ei, deg);
    scan1_kernel<<<SCAN_NB, 256, 0, stream>>>(deg, bsum);
    scan2_kernel<<<1, 512, 0, stream>>>(bsum);
    scan3_kernel<<<SCAN_NB, 256, 0, stream>>>(deg, bsum, rowptr, cursor);
    scatter_kernel<<<(E_TOTC + 255) / 256, 256, 0, stream>>>(ei, cursor, colsrc);

    agg_csr_kernel<<<N_NODESC / 2, 256, 0, stream>>>(rowptr, colsrc, a_src, a_dst, h, bias, out);
}

// Round 3
// 569.897 us; speedup vs baseline: 23.4945x; 1.2521x over previous
//
#include <hip/hip_runtime.h>

#define N_NODESC 100000
#define N_EDGESC 1600000
#define IN_CHC 64
#define HEADSC 8
#define OUT_CHC 16
#define HCC 128                      // HEADS*OUT_CH
#define E_TOTC (N_EDGESC + N_NODESC) // edges + self loops
#define SCAN_NB 391                  // ceil(N_NODES/256)

__device__ __forceinline__ float lrelu(float v) {
    return v < 0.f ? 0.2f * v : v;
}
__device__ __forceinline__ unsigned short f2bf(float f) {   // RNE bf16
    unsigned u = __float_as_uint(f);
    unsigned r = ((u >> 16) & 1u) + 0x7fffu;
    return (unsigned short)((u + r) >> 16);
}

// ---- transpose W [128][64] -> WT [64][128] (k-major) ----
__global__ void wt_kernel(const float* __restrict__ W, float* __restrict__ WT) {
    int t = blockIdx.x * 256 + threadIdx.x;
    if (t < HCC * IN_CHC) {
        int k = t >> 7, c = t & 127;
        WT[t] = W[c * IN_CHC + k];
    }
}

// ---- projection GEMM + fused attention dots ----
// h16[N][128] = bf16(x @ W^T); a_src/a_dst[N][8] = per-head dots (fp32-exact).
__launch_bounds__(256, 2)
__global__ void proj_kernel(const float* __restrict__ x, const float* __restrict__ WT,
                            const float* __restrict__ att_src, const float* __restrict__ att_dst,
                            unsigned short* __restrict__ h16,
                            float* __restrict__ a_src, float* __restrict__ a_dst) {
    __shared__ float xs[128][68];
    __shared__ float ws[64][128];
    const int t = threadIdx.x;
    const int row0 = blockIdx.x * 128;

    const float4* wt4 = (const float4*)WT;
    float4* ws4 = (float4*)&ws[0][0];
#pragma unroll
    for (int j = 0; j < 8; ++j) ws4[t + 256 * j] = wt4[t + 256 * j];

#pragma unroll
    for (int j = 0; j < 8; ++j) {
        int f = (t + 256 * j) * 4;
        int r = f >> 6, k = f & 63;
        int gr = row0 + r;
        if (gr >= N_NODESC) gr = N_NODESC - 1;
        float4 v = *(const float4*)&x[(size_t)gr * IN_CHC + k];
        *(float4*)&xs[r][k] = v;
    }
    __syncthreads();

    const int rg = t & 15;
    const int cg = t >> 4;
    float acc[8][8];
#pragma unroll
    for (int i = 0; i < 8; ++i)
#pragma unroll
        for (int j = 0; j < 8; ++j) acc[i][j] = 0.f;

#pragma unroll 4
    for (int k = 0; k < 64; ++k) {
        float xv[8];
#pragma unroll
        for (int i = 0; i < 8; ++i) xv[i] = xs[rg + 16 * i][k];
        float4 w0 = *(const float4*)&ws[k][4 * cg];
        float4 w1 = *(const float4*)&ws[k][64 + 4 * cg];
#pragma unroll
        for (int i = 0; i < 8; ++i) {
            acc[i][0] += xv[i] * w0.x; acc[i][1] += xv[i] * w0.y;
            acc[i][2] += xv[i] * w0.z; acc[i][3] += xv[i] * w0.w;
            acc[i][4] += xv[i] * w1.x; acc[i][5] += xv[i] * w1.y;
            acc[i][6] += xv[i] * w1.z; acc[i][7] += xv[i] * w1.w;
        }
    }

    // epilogue: bf16 h store + per-head attention dots.
    // thread's cols: 4cg+q (head hA=cg>>2, j=4*(cg&3)+q) and 64+4cg+q (head hB=hA+4).
    const int cg4 = cg & 3;
    const int hA = cg >> 2, hB = (cg >> 2) + 4;
    float4 sA = *(const float4*)&att_src[hA * 16 + 4 * cg4];
    float4 dA = *(const float4*)&att_dst[hA * 16 + 4 * cg4];
    float4 sB = *(const float4*)&att_src[hB * 16 + 4 * cg4];
    float4 dB = *(const float4*)&att_dst[hB * 16 + 4 * cg4];

#pragma unroll
    for (int i = 0; i < 8; ++i) {
        int gr = row0 + rg + 16 * i;
        float asA = acc[i][0] * sA.x + acc[i][1] * sA.y + acc[i][2] * sA.z + acc[i][3] * sA.w;
        float adA = acc[i][0] * dA.x + acc[i][1] * dA.y + acc[i][2] * dA.z + acc[i][3] * dA.w;
        float asB = acc[i][4] * sB.x + acc[i][5] * sB.y + acc[i][6] * sB.z + acc[i][7] * sB.w;
        float adB = acc[i][4] * dB.x + acc[i][5] * dB.y + acc[i][6] * dB.z + acc[i][7] * dB.w;
        // reduce over the 4 lanes (cg&3 = 0..3) holding this head's 16 cols
        asA += __shfl_xor(asA, 16); asA += __shfl_xor(asA, 32);
        adA += __shfl_xor(adA, 16); adA += __shfl_xor(adA, 32);
        asB += __shfl_xor(asB, 16); asB += __shfl_xor(asB, 32);
        adB += __shfl_xor(adB, 16); adB += __shfl_xor(adB, 32);
        if (gr < N_NODESC) {
            ushort4 p0, p1;
            p0.x = f2bf(acc[i][0]); p0.y = f2bf(acc[i][1]); p0.z = f2bf(acc[i][2]); p0.w = f2bf(acc[i][3]);
            p1.x = f2bf(acc[i][4]); p1.y = f2bf(acc[i][5]); p1.z = f2bf(acc[i][6]); p1.w = f2bf(acc[i][7]);
            *(ushort4*)&h16[(size_t)gr * HCC + 4 * cg] = p0;
            *(ushort4*)&h16[(size_t)gr * HCC + 64 + 4 * cg] = p1;
            if (cg4 == 0) {
                a_src[(size_t)gr * 8 + hA] = asA;
                a_dst[(size_t)gr * 8 + hA] = adA;
                a_src[(size_t)gr * 8 + hB] = asB;
                a_dst[(size_t)gr * 8 + hB] = adB;
            }
        }
    }
}

// ---- CSR build: degree histogram over dst (incl. self loops) ----
__global__ void deg_kernel(const int* __restrict__ ei, int* __restrict__ deg) {
    int e = blockIdx.x * 256 + threadIdx.x;
    if (e >= E_TOTC) return;
    int d = (e < N_EDGESC) ? ei[N_EDGESC + e] : (e - N_EDGESC);
    atomicAdd(&deg[d], 1);
}

__global__ void scan1_kernel(const int* __restrict__ deg, int* __restrict__ bsum) {
    __shared__ int lds[256];
    int i = blockIdx.x * 256 + threadIdx.x;
    lds[threadIdx.x] = (i < N_NODESC) ? deg[i] : 0;
    __syncthreads();
    for (int off = 128; off > 0; off >>= 1) {
        if (threadIdx.x < off) lds[threadIdx.x] += lds[threadIdx.x + off];
        __syncthreads();
    }
    if (threadIdx.x == 0) bsum[blockIdx.x] = lds[0];
}

__global__ void scan2_kernel(int* __restrict__ bsum) {
    __shared__ int lds[512];
    int t = threadIdx.x;
    lds[t] = (t < SCAN_NB) ? bsum[t] : 0;
    __syncthreads();
    for (int off = 1; off < 512; off <<= 1) {
        int u = 0;
        if (t >= off) u = lds[t - off];
        __syncthreads();
        if (t >= off) lds[t] += u;
        __syncthreads();
    }
    if (t < SCAN_NB) bsum[t] = (t == 0) ? 0 : lds[t - 1];
}

__global__ void scan3_kernel(const int* __restrict__ deg, const int* __restrict__ bsum,
                             int* __restrict__ rowptr, int* __restrict__ cursor) {
    __shared__ int lds[256];
    int t = threadIdx.x;
    int i = blockIdx.x * 256 + t;
    int v = (i < N_NODESC) ? deg[i] : 0;
    lds[t] = v;
    __syncthreads();
    for (int off = 1; off < 256; off <<= 1) {
        int u = 0;
        if (t >= off) u = lds[t - off];
        __syncthreads();
        if (t >= off) lds[t] += u;
        __syncthreads();
    }
    int excl = bsum[blockIdx.x] + lds[t] - v;
    if (i < N_NODESC) { rowptr[i] = excl; cursor[i] = excl; }
    if (i == 0) rowptr[N_NODESC] = E_TOTC;
}

__global__ void scatter_kernel(const int* __restrict__ ei, int* __restrict__ cursor,
                               int* __restrict__ colsrc) {
    int e = blockIdx.x * 256 + threadIdx.x;
    if (e >= E_TOTC) return;
    int s, d;
    if (e < N_EDGESC) { s = ei[e]; d = ei[N_EDGESC + e]; }
    else              { s = d = e - N_EDGESC; }
    int pos = atomicAdd(&cursor[d], 1);
    colsrc[pos] = s;
}

// ---- fused online-softmax gather aggregation ----
// 128 threads own one dst node's 128 channels; single pass over in-edges.
__launch_bounds__(256, 8)
__global__ void agg_csr_kernel(const int* __restrict__ rowptr, const int* __restrict__ colsrc,
                               const float* __restrict__ a_src, const float* __restrict__ a_dst,
                               const unsigned short* __restrict__ h16,
                               const float* __restrict__ bias, float* __restrict__ out) {
    int t = threadIdx.x;
    int n = blockIdx.x * 2 + (t >> 7);
    int c = t & 127, hd = c >> 4;
    int beg = rowptr[n], end = rowptr[n + 1];
    float ad = a_dst[(size_t)n * 8 + hd];

    float m = -1e30f, den = 0.f, acc = 0.f;
    int s = colsrc[beg];
    for (int p = beg; p < end; ++p) {
        int sn = (p + 1 < end) ? colsrc[p + 1] : 0;
        float l = lrelu(a_src[(size_t)s * 8 + hd] + ad);
        float hv = __uint_as_float((unsigned)h16[(size_t)s * HCC + c] << 16);
        float mn = fmaxf(m, l);
        float sc = __expf(m - mn);
        float e  = __expf(l - mn);
        den = den * sc + e;
        acc = acc * sc + e * hv;
        m = mn;
        s = sn;
    }
    out[(size_t)n * HCC + c] = fmaxf(acc / (den + 1e-16f) + bias[c], 0.f);
}

extern "C" void kernel_launch(void* const* d_in, const int* in_sizes, int n_in,
                              void* d_out, int out_size, void* d_ws, size_t ws_size,
                              hipStream_t stream) {
    const float* x       = (const float*)d_in[0];
    const int*   ei      = (const int*)d_in[1];
    const float* W       = (const float*)d_in[2];
    const float* att_src = (const float*)d_in[3];
    const float* att_dst = (const float*)d_in[4];
    const float* bias    = (const float*)d_in[5];
    float* out = (float*)d_out;

    float* ws    = (float*)d_ws;
    unsigned short* h16 = (unsigned short*)ws;   // 12,800,000 ushorts (6.4M float slots)
    float* a_src = ws + 6400000;                 //    800,000
    float* a_dst = a_src + 800000;               //    800,000
    float* WT    = a_dst + 800000;               //      8,192
    int* deg     = (int*)(WT + 8192);            //    100,000
    int* rowptr  = deg + 100000;                 //    100,001
    int* cursor  = rowptr + 100001;              //    100,000
    int* bsum    = cursor + 100000;              //        512
    int* colsrc  = bsum + 512;                   //  1,700,000

    hipMemsetAsync(deg, 0, 100000 * sizeof(int), stream);

    wt_kernel<<<32, 256, 0, stream>>>(W, WT);
    proj_kernel<<<(N_NODESC + 127) / 128, 256, 0, stream>>>(x, WT, att_src, att_dst,
                                                            h16, a_src, a_dst);
    deg_kernel<<<(E_TOTC + 255) / 256, 256, 0, stream>>>(ei, deg);
    scan1_kernel<<<SCAN_NB, 256, 0, stream>>>(deg, bsum);
    scan2_kernel<<<1, 512, 0, stream>>>(bsum);
    scan3_kernel<<<SCAN_NB, 256, 0, stream>>>(deg, bsum, rowptr, cursor);
    scatter_kernel<<<(E_TOTC + 255) / 256, 256, 0, stream>>>(ei, cursor, colsrc);

    agg_csr_kernel<<<N_NODESC / 2, 256, 0, stream>>>(rowptr, colsrc, a_src, a_dst, h16, bias, out);
}

// Round 4
// 281.077 us; speedup vs baseline: 47.6363x; 2.0275x over previous
//
#include <hip/hip_runtime.h>

#define N_NODESC 100000
#define N_EDGESC 1600000
#define IN_CHC 64
#define HEADSC 8
#define OUT_CHC 16
#define HCC 128                      // HEADS*OUT_CH
#define E_TOTC (N_EDGESC + N_NODESC) // edges + self loops
#define SCAN_NB 391                  // ceil(N_NODES/256)

__device__ __forceinline__ float lrelu(float v) {
    return v < 0.f ? 0.2f * v : v;
}
__device__ __forceinline__ unsigned short f2bf(float f) {   // RNE bf16
    unsigned u = __float_as_uint(f);
    unsigned r = ((u >> 16) & 1u) + 0x7fffu;
    return (unsigned short)((u + r) >> 16);
}

// ---- transpose W [128][64] -> WT [64][128] (k-major) ----
__global__ void wt_kernel(const float* __restrict__ W, float* __restrict__ WT) {
    int t = blockIdx.x * 256 + threadIdx.x;
    if (t < HCC * IN_CHC) {
        int k = t >> 7, c = t & 127;
        WT[t] = W[c * IN_CHC + k];
    }
}

// ---- projection GEMM + fused attention dots ----
// h16[N][128] = bf16(x @ W^T); a_src/a_dst[N][8] = per-head dots (fp32-exact).
__launch_bounds__(256, 2)
__global__ void proj_kernel(const float* __restrict__ x, const float* __restrict__ WT,
                            const float* __restrict__ att_src, const float* __restrict__ att_dst,
                            unsigned short* __restrict__ h16,
                            float* __restrict__ a_src, float* __restrict__ a_dst) {
    __shared__ float xs[128][68];
    __shared__ float ws[64][128];
    const int t = threadIdx.x;
    const int row0 = blockIdx.x * 128;

    const float4* wt4 = (const float4*)WT;
    float4* ws4 = (float4*)&ws[0][0];
#pragma unroll
    for (int j = 0; j < 8; ++j) ws4[t + 256 * j] = wt4[t + 256 * j];

#pragma unroll
    for (int j = 0; j < 8; ++j) {
        int f = (t + 256 * j) * 4;
        int r = f >> 6, k = f & 63;
        int gr = row0 + r;
        if (gr >= N_NODESC) gr = N_NODESC - 1;
        float4 v = *(const float4*)&x[(size_t)gr * IN_CHC + k];
        *(float4*)&xs[r][k] = v;
    }
    __syncthreads();

    const int rg = t & 15;
    const int cg = t >> 4;
    float acc[8][8];
#pragma unroll
    for (int i = 0; i < 8; ++i)
#pragma unroll
        for (int j = 0; j < 8; ++j) acc[i][j] = 0.f;

#pragma unroll 4
    for (int k = 0; k < 64; ++k) {
        float xv[8];
#pragma unroll
        for (int i = 0; i < 8; ++i) xv[i] = xs[rg + 16 * i][k];
        float4 w0 = *(const float4*)&ws[k][4 * cg];
        float4 w1 = *(const float4*)&ws[k][64 + 4 * cg];
#pragma unroll
        for (int i = 0; i < 8; ++i) {
            acc[i][0] += xv[i] * w0.x; acc[i][1] += xv[i] * w0.y;
            acc[i][2] += xv[i] * w0.z; acc[i][3] += xv[i] * w0.w;
            acc[i][4] += xv[i] * w1.x; acc[i][5] += xv[i] * w1.y;
            acc[i][6] += xv[i] * w1.z; acc[i][7] += xv[i] * w1.w;
        }
    }

    const int cg4 = cg & 3;
    const int hA = cg >> 2, hB = (cg >> 2) + 4;
    float4 sA = *(const float4*)&att_src[hA * 16 + 4 * cg4];
    float4 dA = *(const float4*)&att_dst[hA * 16 + 4 * cg4];
    float4 sB = *(const float4*)&att_src[hB * 16 + 4 * cg4];
    float4 dB = *(const float4*)&att_dst[hB * 16 + 4 * cg4];

#pragma unroll
    for (int i = 0; i < 8; ++i) {
        int gr = row0 + rg + 16 * i;
        float asA = acc[i][0] * sA.x + acc[i][1] * sA.y + acc[i][2] * sA.z + acc[i][3] * sA.w;
        float adA = acc[i][0] * dA.x + acc[i][1] * dA.y + acc[i][2] * dA.z + acc[i][3] * dA.w;
        float asB = acc[i][4] * sB.x + acc[i][5] * sB.y + acc[i][6] * sB.z + acc[i][7] * sB.w;
        float adB = acc[i][4] * dB.x + acc[i][5] * dB.y + acc[i][6] * dB.z + acc[i][7] * dB.w;
        asA += __shfl_xor(asA, 16); asA += __shfl_xor(asA, 32);
        adA += __shfl_xor(adA, 16); adA += __shfl_xor(adA, 32);
        asB += __shfl_xor(asB, 16); asB += __shfl_xor(asB, 32);
        adB += __shfl_xor(adB, 16); adB += __shfl_xor(adB, 32);
        if (gr < N_NODESC) {
            ushort4 p0, p1;
            p0.x = f2bf(acc[i][0]); p0.y = f2bf(acc[i][1]); p0.z = f2bf(acc[i][2]); p0.w = f2bf(acc[i][3]);
            p1.x = f2bf(acc[i][4]); p1.y = f2bf(acc[i][5]); p1.z = f2bf(acc[i][6]); p1.w = f2bf(acc[i][7]);
            *(ushort4*)&h16[(size_t)gr * HCC + 4 * cg] = p0;
            *(ushort4*)&h16[(size_t)gr * HCC + 64 + 4 * cg] = p1;
            if (cg4 == 0) {
                a_src[(size_t)gr * 8 + hA] = asA;
                a_dst[(size_t)gr * 8 + hA] = adA;
                a_src[(size_t)gr * 8 + hB] = asB;
                a_dst[(size_t)gr * 8 + hB] = adB;
            }
        }
    }
}

// ---- CSR build: degree histogram + intra-segment position in ONE atomic pass ----
__global__ void pos_kernel(const int* __restrict__ ei, int* __restrict__ deg,
                           int* __restrict__ posb) {
    int e = blockIdx.x * 256 + threadIdx.x;
    if (e >= E_TOTC) return;
    int d = (e < N_EDGESC) ? ei[N_EDGESC + e] : (e - N_EDGESC);
    posb[e] = atomicAdd(&deg[d], 1);
}

__global__ void scan1_kernel(const int* __restrict__ deg, int* __restrict__ bsum) {
    __shared__ int lds[256];
    int i = blockIdx.x * 256 + threadIdx.x;
    lds[threadIdx.x] = (i < N_NODESC) ? deg[i] : 0;
    __syncthreads();
    for (int off = 128; off > 0; off >>= 1) {
        if (threadIdx.x < off) lds[threadIdx.x] += lds[threadIdx.x + off];
        __syncthreads();
    }
    if (threadIdx.x == 0) bsum[blockIdx.x] = lds[0];
}

__global__ void scan2_kernel(int* __restrict__ bsum) {
    __shared__ int lds[512];
    int t = threadIdx.x;
    lds[t] = (t < SCAN_NB) ? bsum[t] : 0;
    __syncthreads();
    for (int off = 1; off < 512; off <<= 1) {
        int u = 0;
        if (t >= off) u = lds[t - off];
        __syncthreads();
        if (t >= off) lds[t] += u;
        __syncthreads();
    }
    if (t < SCAN_NB) bsum[t] = (t == 0) ? 0 : lds[t - 1];
}

__global__ void scan3_kernel(const int* __restrict__ deg, const int* __restrict__ bsum,
                             int* __restrict__ rowptr) {
    __shared__ int lds[256];
    int t = threadIdx.x;
    int i = blockIdx.x * 256 + t;
    int v = (i < N_NODESC) ? deg[i] : 0;
    lds[t] = v;
    __syncthreads();
    for (int off = 1; off < 256; off <<= 1) {
        int u = 0;
        if (t >= off) u = lds[t - off];
        __syncthreads();
        if (t >= off) lds[t] += u;
        __syncthreads();
    }
    int excl = bsum[blockIdx.x] + lds[t] - v;
    if (i < N_NODESC) rowptr[i] = excl;
    if (i == 0) rowptr[N_NODESC] = E_TOTC;
}

// ---- scatter edges into CSR order (no atomics: position precomputed) ----
__global__ void scatter_kernel(const int* __restrict__ ei, const int* __restrict__ rowptr,
                               const int* __restrict__ posb, int* __restrict__ colsrc) {
    int e = blockIdx.x * 256 + threadIdx.x;
    if (e >= E_TOTC) return;
    int s, d;
    if (e < N_EDGESC) { s = ei[e]; d = ei[N_EDGESC + e]; }
    else              { s = d = e - N_EDGESC; }
    colsrc[rowptr[d] + posb[e]] = s;
}

// ---- fused chunked-online-softmax gather aggregation ----
// One wave per node: lane L owns channels 2L, 2L+1 (head = L>>3).
// Phase A per 8-edge chunk: lanes = (head, e-slot); softmax stats via shfl_xor tree.
// Phase B: per edge, broadcast (src, p) via shfl; 1x u32 (2xbf16) load + 2 FMA per lane.
__launch_bounds__(256, 8)
__global__ void agg_csr_kernel(const int* __restrict__ rowptr, const int* __restrict__ colsrc,
                               const float* __restrict__ a_src, const float* __restrict__ a_dst,
                               const unsigned* __restrict__ h32,
                               const float* __restrict__ bias, float* __restrict__ out) {
    const int t = threadIdx.x;
    const int L = t & 63;
    const int n = blockIdx.x * 4 + (t >> 6);
    const int hd = L >> 3;          // head (phase A) == channel head (phase B)
    const int eL = L & 7;           // e-slot within chunk
    const int gbase = L & ~7;       // first lane of my head group

    const int beg = rowptr[n], end = rowptr[n + 1];
    const float ad = a_dst[n * 8 + hd];

    float m = -1e30f, den = 0.f, acc0 = 0.f, acc1 = 0.f;

    for (int p0 = beg; p0 < end; p0 += 8) {
        const int cnt = min(8, end - p0);
        const bool valid = eL < cnt;
        int s_reg = 0;
        float l = -1e30f;
        if (valid) {
            s_reg = colsrc[p0 + eL];
            l = lrelu(a_src[s_reg * 8 + hd] + ad);
        }
        float mx = l;
        mx = fmaxf(mx, __shfl_xor(mx, 1));
        mx = fmaxf(mx, __shfl_xor(mx, 2));
        mx = fmaxf(mx, __shfl_xor(mx, 4));
        const float mn = fmaxf(m, mx);
        const float sc = __expf(m - mn);
        float p = valid ? __expf(l - mn) : 0.f;
        float cs = p;
        cs += __shfl_xor(cs, 1);
        cs += __shfl_xor(cs, 2);
        cs += __shfl_xor(cs, 4);
        den = den * sc + cs;
        acc0 *= sc; acc1 *= sc;
        m = mn;
#pragma unroll 4
        for (int e = 0; e < cnt; ++e) {
            const int src = __shfl(s_reg, gbase + e);
            const float pv = __shfl(p, gbase + e);
            const unsigned u = h32[src * 64 + L];
            const float f0 = __uint_as_float(u << 16);
            const float f1 = __uint_as_float(u & 0xffff0000u);
            acc0 = fmaf(pv, f0, acc0);
            acc1 = fmaf(pv, f1, acc1);
        }
    }
    const float inv = 1.f / (den + 1e-16f);
    const float2 b = ((const float2*)bias)[L];
    float2 o;
    o.x = fmaxf(acc0 * inv + b.x, 0.f);
    o.y = fmaxf(acc1 * inv + b.y, 0.f);
    ((float2*)out)[n * 64 + L] = o;
}

extern "C" void kernel_launch(void* const* d_in, const int* in_sizes, int n_in,
                              void* d_out, int out_size, void* d_ws, size_t ws_size,
                              hipStream_t stream) {
    const float* x       = (const float*)d_in[0];
    const int*   ei      = (const int*)d_in[1];
    const float* W       = (const float*)d_in[2];
    const float* att_src = (const float*)d_in[3];
    const float* att_dst = (const float*)d_in[4];
    const float* bias    = (const float*)d_in[5];
    float* out = (float*)d_out;

    float* ws    = (float*)d_ws;
    unsigned short* h16 = (unsigned short*)ws;   // 12,800,000 ushorts (6.4M float slots)
    float* a_src = ws + 6400000;                 //    800,000
    float* a_dst = a_src + 800000;               //    800,000
    float* WT    = a_dst + 800000;               //      8,192
    int* deg     = (int*)(WT + 8192);            //    100,000
    int* rowptr  = deg + 100000;                 //    100,001
    int* bsum    = rowptr + 100001;              //        512
    int* posb    = bsum + 512;                   //  1,700,000
    int* colsrc  = posb + 1700000;               //  1,700,000

    hipMemsetAsync(deg, 0, 100000 * sizeof(int), stream);

    wt_kernel<<<32, 256, 0, stream>>>(W, WT);
    proj_kernel<<<(N_NODESC + 127) / 128, 256, 0, stream>>>(x, WT, att_src, att_dst,
                                                            h16, a_src, a_dst);
    pos_kernel<<<(E_TOTC + 255) / 256, 256, 0, stream>>>(ei, deg, posb);
    scan1_kernel<<<SCAN_NB, 256, 0, stream>>>(deg, bsum);
    scan2_kernel<<<1, 512, 0, stream>>>(bsum);
    scan3_kernel<<<SCAN_NB, 256, 0, stream>>>(deg, bsum, rowptr);
    scatter_kernel<<<(E_TOTC + 255) / 256, 256, 0, stream>>>(ei, rowptr, posb, colsrc);

    agg_csr_kernel<<<N_NODESC / 4, 256, 0, stream>>>(rowptr, colsrc, a_src, a_dst,
                                                     (const unsigned*)h16, bias, out);
}

// Round 5
// 219.711 us; speedup vs baseline: 60.9412x; 1.2793x over previous
//
#include <hip/hip_runtime.h>

#define N_NODESC 100000
#define N_EDGESC 1600000
#define IN_CHC 64
#define HEADSC 8
#define OUT_CHC 16
#define HCC 128                      // HEADS*OUT_CH
#define E_TOTC (N_EDGESC + N_NODESC) // edges + self loops
#define SCAN_NB 391                  // ceil(N_NODES/256)
#define PROJ_NB 782                  // ceil(N_NODES/128)
#define POS_NB 831                   // ceil(E_TOT/2048)

__device__ __forceinline__ float lrelu(float v) {
    return v < 0.f ? 0.2f * v : v;
}
__device__ __forceinline__ unsigned short f2bf(float f) {   // RNE bf16
    unsigned u = __float_as_uint(f);
    unsigned r = ((u >> 16) & 1u) + 0x7fffu;
    return (unsigned short)((u + r) >> 16);
}

// ---- fused: projection GEMM (+attention dots, bf16 h store) | pos/deg pass ----
// blocks [0, PROJ_NB): proj; blocks [PROJ_NB, PROJ_NB+POS_NB): CSR position pass.
__launch_bounds__(256, 2)
__global__ void proj_pos_kernel(const float* __restrict__ x, const float* __restrict__ W,
                                const float* __restrict__ att_src, const float* __restrict__ att_dst,
                                unsigned short* __restrict__ h16,
                                float* __restrict__ a_src, float* __restrict__ a_dst,
                                const int* __restrict__ ei, int* __restrict__ deg,
                                int* __restrict__ posb) {
    const int t = threadIdx.x;

    if (blockIdx.x >= PROJ_NB) {
        // ---------------- pos part: deg histogram + intra-segment position ----------------
        const int e0 = (blockIdx.x - PROJ_NB) * 2048 + t;
#pragma unroll
        for (int j = 0; j < 8; ++j) {
            int e = e0 + 256 * j;
            if (e < E_TOTC) {
                int d = (e < N_EDGESC) ? ei[N_EDGESC + e] : (e - N_EDGESC);
                posb[e] = atomicAdd(&deg[d], 1);
            }
        }
        return;
    }

    // ---------------- proj part ----------------
    __shared__ float xs[128][68];
    __shared__ float ws[64][132];   // W^T staged k-major, padded
    const int row0 = blockIdx.x * 128;

    // transpose W [128][64] row-major -> ws[k][c]
    const float4* W4 = (const float4*)W;   // 2048 float4
#pragma unroll
    for (int j = 0; j < 8; ++j) {
        int q = t + 256 * j;
        float4 v = W4[q];
        int c = q >> 4;           // output channel 0..127
        int k0 = (q & 15) * 4;    // k 0..60
        ws[k0 + 0][c] = v.x; ws[k0 + 1][c] = v.y;
        ws[k0 + 2][c] = v.z; ws[k0 + 3][c] = v.w;
    }

    // stage x tile
#pragma unroll
    for (int j = 0; j < 8; ++j) {
        int f = (t + 256 * j) * 4;
        int r = f >> 6, k = f & 63;
        int gr = row0 + r;
        if (gr >= N_NODESC) gr = N_NODESC - 1;
        float4 v = *(const float4*)&x[(size_t)gr * IN_CHC + k];
        *(float4*)&xs[r][k] = v;
    }
    __syncthreads();

    const int rg = t & 15;
    const int cg = t >> 4;
    float acc[8][8];
#pragma unroll
    for (int i = 0; i < 8; ++i)
#pragma unroll
        for (int j = 0; j < 8; ++j) acc[i][j] = 0.f;

#pragma unroll 4
    for (int k = 0; k < 64; ++k) {
        float xv[8];
#pragma unroll
        for (int i = 0; i < 8; ++i) xv[i] = xs[rg + 16 * i][k];
        float4 w0 = *(const float4*)&ws[k][4 * cg];
        float4 w1 = *(const float4*)&ws[k][64 + 4 * cg];
#pragma unroll
        for (int i = 0; i < 8; ++i) {
            acc[i][0] += xv[i] * w0.x; acc[i][1] += xv[i] * w0.y;
            acc[i][2] += xv[i] * w0.z; acc[i][3] += xv[i] * w0.w;
            acc[i][4] += xv[i] * w1.x; acc[i][5] += xv[i] * w1.y;
            acc[i][6] += xv[i] * w1.z; acc[i][7] += xv[i] * w1.w;
        }
    }

    const int cg4 = cg & 3;
    const int hA = cg >> 2, hB = (cg >> 2) + 4;
    float4 sA = *(const float4*)&att_src[hA * 16 + 4 * cg4];
    float4 dA = *(const float4*)&att_dst[hA * 16 + 4 * cg4];
    float4 sB = *(const float4*)&att_src[hB * 16 + 4 * cg4];
    float4 dB = *(const float4*)&att_dst[hB * 16 + 4 * cg4];

#pragma unroll
    for (int i = 0; i < 8; ++i) {
        int gr = row0 + rg + 16 * i;
        float asA = acc[i][0] * sA.x + acc[i][1] * sA.y + acc[i][2] * sA.z + acc[i][3] * sA.w;
        float adA = acc[i][0] * dA.x + acc[i][1] * dA.y + acc[i][2] * dA.z + acc[i][3] * dA.w;
        float asB = acc[i][4] * sB.x + acc[i][5] * sB.y + acc[i][6] * sB.z + acc[i][7] * sB.w;
        float adB = acc[i][4] * dB.x + acc[i][5] * dB.y + acc[i][6] * dB.z + acc[i][7] * dB.w;
        asA += __shfl_xor(asA, 16); asA += __shfl_xor(asA, 32);
        adA += __shfl_xor(adA, 16); adA += __shfl_xor(adA, 32);
        asB += __shfl_xor(asB, 16); asB += __shfl_xor(asB, 32);
        adB += __shfl_xor(adB, 16); adB += __shfl_xor(adB, 32);
        if (gr < N_NODESC) {
            ushort4 p0, p1;
            p0.x = f2bf(acc[i][0]); p0.y = f2bf(acc[i][1]); p0.z = f2bf(acc[i][2]); p0.w = f2bf(acc[i][3]);
            p1.x = f2bf(acc[i][4]); p1.y = f2bf(acc[i][5]); p1.z = f2bf(acc[i][6]); p1.w = f2bf(acc[i][7]);
            *(ushort4*)&h16[(size_t)gr * HCC + 4 * cg] = p0;
            *(ushort4*)&h16[(size_t)gr * HCC + 64 + 4 * cg] = p1;
            if (cg4 == 0) {
                a_src[(size_t)gr * 8 + hA] = asA;
                a_dst[(size_t)gr * 8 + hA] = adA;
                a_src[(size_t)gr * 8 + hB] = asB;
                a_dst[(size_t)gr * 8 + hB] = adB;
            }
        }
    }
}

__global__ void scan1_kernel(const int* __restrict__ deg, int* __restrict__ bsum) {
    __shared__ int lds[256];
    int i = blockIdx.x * 256 + threadIdx.x;
    lds[threadIdx.x] = (i < N_NODESC) ? deg[i] : 0;
    __syncthreads();
    for (int off = 128; off > 0; off >>= 1) {
        if (threadIdx.x < off) lds[threadIdx.x] += lds[threadIdx.x + off];
        __syncthreads();
    }
    if (threadIdx.x == 0) bsum[blockIdx.x] = lds[0];
}

__global__ void scan2_kernel(int* __restrict__ bsum) {
    __shared__ int lds[512];
    int t = threadIdx.x;
    lds[t] = (t < SCAN_NB) ? bsum[t] : 0;
    __syncthreads();
    for (int off = 1; off < 512; off <<= 1) {
        int u = 0;
        if (t >= off) u = lds[t - off];
        __syncthreads();
        if (t >= off) lds[t] += u;
        __syncthreads();
    }
    if (t < SCAN_NB) bsum[t] = (t == 0) ? 0 : lds[t - 1];
}

__global__ void scan3_kernel(const int* __restrict__ deg, const int* __restrict__ bsum,
                             int* __restrict__ rowptr) {
    __shared__ int lds[256];
    int t = threadIdx.x;
    int i = blockIdx.x * 256 + t;
    int v = (i < N_NODESC) ? deg[i] : 0;
    lds[t] = v;
    __syncthreads();
    for (int off = 1; off < 256; off <<= 1) {
        int u = 0;
        if (t >= off) u = lds[t - off];
        __syncthreads();
        if (t >= off) lds[t] += u;
        __syncthreads();
    }
    int excl = bsum[blockIdx.x] + lds[t] - v;
    if (i < N_NODESC) rowptr[i] = excl;
    if (i == 0) rowptr[N_NODESC] = E_TOTC;
}

__global__ void scatter_kernel(const int* __restrict__ ei, const int* __restrict__ rowptr,
                               const int* __restrict__ posb, int* __restrict__ colsrc) {
    int e = blockIdx.x * 256 + threadIdx.x;
    if (e >= E_TOTC) return;
    int s, d;
    if (e < N_EDGESC) { s = ei[e]; d = ei[N_EDGESC + e]; }
    else              { s = d = e - N_EDGESC; }
    colsrc[rowptr[d] + posb[e]] = s;
}

// ---- fused chunked-online-softmax gather aggregation, lane-local p ----
// One wave per node. Lane L = (head hd=L>>3, e-slot eL=L&7). Per 8-edge chunk:
// lane loads its OWN edge's src, a_src, and 16 channels of its head (2x dwordx4);
// softmax weight p stays lane-local -> zero bpermutes in the FMA phase.
// Epilogue: 48-shfl reduce over the 8 e-slot lanes, static select, float2 store.
__launch_bounds__(256, 8)
__global__ void agg_csr_kernel(const int* __restrict__ rowptr, const int* __restrict__ colsrc,
                               const float* __restrict__ a_src, const float* __restrict__ a_dst,
                               const unsigned* __restrict__ h32,
                               const float* __restrict__ bias, float* __restrict__ out) {
    const int t = threadIdx.x;
    const int L = t & 63;
    const int n = blockIdx.x * 4 + (t >> 6);
    const int hd = L >> 3;
    const int eL = L & 7;

    const int beg = rowptr[n], end = rowptr[n + 1];
    const float ad = a_dst[n * 8 + hd];

    float m = -1e30f, den = 0.f;
    float acc[16];
#pragma unroll
    for (int j = 0; j < 16; ++j) acc[j] = 0.f;

    // prefetch chunk 0
    bool vld = eL < (end - beg);
    int s = vld ? colsrc[beg + eL] : 0;
    float av = vld ? a_src[s * 8 + hd] : 0.f;

    for (int p0 = beg; p0 < end; p0 += 8) {
        // issue current chunk's h loads early
        uint4 ha = make_uint4(0, 0, 0, 0), hb = make_uint4(0, 0, 0, 0);
        if (vld) {
            const uint4* hp = (const uint4*)(h32 + (size_t)s * 64 + hd * 8);
            ha = hp[0];
            hb = hp[1];
        }
        // prefetch next chunk (colsrc + a_src) under the softmax/FMA phase
        bool vld2 = (p0 + 8 + eL) < end;
        int s2 = vld2 ? colsrc[p0 + 8 + eL] : 0;
        float av2 = vld2 ? a_src[s2 * 8 + hd] : 0.f;

        // online softmax over this chunk (within 8-lane head group)
        float l = vld ? lrelu(av + ad) : -1e30f;
        float mx = l;
        mx = fmaxf(mx, __shfl_xor(mx, 1));
        mx = fmaxf(mx, __shfl_xor(mx, 2));
        mx = fmaxf(mx, __shfl_xor(mx, 4));
        const float mn = fmaxf(m, mx);
        const float sc = __expf(m - mn);
        float p = vld ? __expf(l - mn) : 0.f;
        float cs = p;
        cs += __shfl_xor(cs, 1);
        cs += __shfl_xor(cs, 2);
        cs += __shfl_xor(cs, 4);
        den = den * sc + cs;
        m = mn;
#pragma unroll
        for (int j = 0; j < 16; ++j) acc[j] *= sc;

        // lane-local FMA: 16 channels of my edge, weighted by my p
        acc[0]  = fmaf(p, __uint_as_float(ha.x << 16),        acc[0]);
        acc[1]  = fmaf(p, __uint_as_float(ha.x & 0xffff0000u), acc[1]);
        acc[2]  = fmaf(p, __uint_as_float(ha.y << 16),        acc[2]);
        acc[3]  = fmaf(p, __uint_as_float(ha.y & 0xffff0000u), acc[3]);
        acc[4]  = fmaf(p, __uint_as_float(ha.z << 16),        acc[4]);
        acc[5]  = fmaf(p, __uint_as_float(ha.z & 0xffff0000u), acc[5]);
        acc[6]  = fmaf(p, __uint_as_float(ha.w << 16),        acc[6]);
        acc[7]  = fmaf(p, __uint_as_float(ha.w & 0xffff0000u), acc[7]);
        acc[8]  = fmaf(p, __uint_as_float(hb.x << 16),        acc[8]);
        acc[9]  = fmaf(p, __uint_as_float(hb.x & 0xffff0000u), acc[9]);
        acc[10] = fmaf(p, __uint_as_float(hb.y << 16),        acc[10]);
        acc[11] = fmaf(p, __uint_as_float(hb.y & 0xffff0000u), acc[11]);
        acc[12] = fmaf(p, __uint_as_float(hb.z << 16),        acc[12]);
        acc[13] = fmaf(p, __uint_as_float(hb.z & 0xffff0000u), acc[13]);
        acc[14] = fmaf(p, __uint_as_float(hb.w << 16),        acc[14]);
        acc[15] = fmaf(p, __uint_as_float(hb.w & 0xffff0000u), acc[15]);

        s = s2; av = av2; vld = vld2;
    }

    // reduce the 8 e-slot lanes of each head group
#pragma unroll
    for (int j = 0; j < 16; ++j) {
        acc[j] += __shfl_xor(acc[j], 1);
        acc[j] += __shfl_xor(acc[j], 2);
        acc[j] += __shfl_xor(acc[j], 4);
    }
    const float inv = 1.f / (den + 1e-16f);
    float ox = acc[0], oy = acc[1];
#pragma unroll
    for (int j = 1; j < 8; ++j) {
        ox = (eL == j) ? acc[2 * j]     : ox;
        oy = (eL == j) ? acc[2 * j + 1] : oy;
    }
    const float2 b = ((const float2*)bias)[L];
    float2 o;
    o.x = fmaxf(ox * inv + b.x, 0.f);
    o.y = fmaxf(oy * inv + b.y, 0.f);
    ((float2*)out)[(size_t)n * 64 + L] = o;
}

extern "C" void kernel_launch(void* const* d_in, const int* in_sizes, int n_in,
                              void* d_out, int out_size, void* d_ws, size_t ws_size,
                              hipStream_t stream) {
    const float* x       = (const float*)d_in[0];
    const int*   ei      = (const int*)d_in[1];
    const float* W       = (const float*)d_in[2];
    const float* att_src = (const float*)d_in[3];
    const float* att_dst = (const float*)d_in[4];
    const float* bias    = (const float*)d_in[5];
    float* out = (float*)d_out;

    float* ws    = (float*)d_ws;
    unsigned short* h16 = (unsigned short*)ws;   // 12,800,000 ushorts (6.4M float slots)
    float* a_src = ws + 6400000;                 //    800,000
    float* a_dst = a_src + 800000;               //    800,000
    int* deg     = (int*)(a_dst + 800000);       //    100,000
    int* rowptr  = deg + 100000;                 //    100,001
    int* bsum    = rowptr + 100001;              //        512
    int* posb    = bsum + 512;                   //  1,700,000
    int* colsrc  = posb + 1700000;               //  1,700,000

    hipMemsetAsync(deg, 0, 100000 * sizeof(int), stream);

    proj_pos_kernel<<<PROJ_NB + POS_NB, 256, 0, stream>>>(x, W, att_src, att_dst,
                                                          h16, a_src, a_dst,
                                                          ei, deg, posb);
    scan1_kernel<<<SCAN_NB, 256, 0, stream>>>(deg, bsum);
    scan2_kernel<<<1, 512, 0, stream>>>(bsum);
    scan3_kernel<<<SCAN_NB, 256, 0, stream>>>(deg, bsum, rowptr);
    scatter_kernel<<<(E_TOTC + 255) / 256, 256, 0, stream>>>(ei, rowptr, posb, colsrc);

    agg_csr_kernel<<<N_NODESC / 4, 256, 0, stream>>>(rowptr, colsrc, a_src, a_dst,
                                                     (const unsigned*)h16, bias, out);
}